// Round 3
// baseline (2239.757 us; speedup 1.0000x reference)
//
#include <hip/hip_runtime.h>
#include <cstdint>

#define BATCH   65536
#define IN_DIM  640
#define LAT_DIM 2560
#define KSEL    32

typedef short  v8s __attribute__((ext_vector_type(8)));
typedef float  v4f __attribute__((ext_vector_type(4)));

__device__ inline void async_load16(void* lds, const void* g) {
  __builtin_amdgcn_global_load_lds(
      (const __attribute__((address_space(1))) unsigned int*)g,
      (__attribute__((address_space(3))) unsigned int*)lds, 16, 0, 0);
}

__device__ inline unsigned short f2bf(float v) {
  unsigned int b = __float_as_uint(v);
  return (unsigned short)((b + 0x7fffu + ((b >> 16) & 1u)) >> 16);
}

// ============ conv fp32 -> bf16, 8 elems/thread ============
__global__ __launch_bounds__(256) void conv_bf16(
    const float* __restrict__ src, unsigned short* __restrict__ dst, int n8)
{
  int i = blockIdx.x * 256 + threadIdx.x;
  if (i >= n8) return;
  const float4* s4 = (const float4*)(src) + i * 2;
  float4 a = s4[0], b = s4[1];
  ushort4 lo = make_ushort4(f2bf(a.x), f2bf(a.y), f2bf(a.z), f2bf(a.w));
  ushort4 hi = make_ushort4(f2bf(b.x), f2bf(b.y), f2bf(b.z), f2bf(b.w));
  *(ushort4*)(dst + (size_t)i * 8)     = lo;
  *(ushort4*)(dst + (size_t)i * 8 + 4) = hi;
}

// ============ transpose Wd [640][2560] -> WdT bf16 [2560][640] ============
__global__ __launch_bounds__(256) void transpose_wd(
    const float* __restrict__ Wd, unsigned short* __restrict__ WdT)
{
  __shared__ float tile[32][33];
  const int tx = threadIdx.x & 31;
  const int ty = threadIdx.x >> 5;
  const int l0 = (blockIdx.x % (LAT_DIM / 32)) * 32;
  const int i0 = (blockIdx.x / (LAT_DIM / 32)) * 32;
#pragma unroll
  for (int s = 0; s < 4; ++s)
    tile[ty + 8 * s][tx] = Wd[(size_t)(i0 + ty + 8 * s) * LAT_DIM + l0 + tx];
  __syncthreads();
#pragma unroll
  for (int s = 0; s < 4; ++s)
    WdT[(size_t)(l0 + ty + 8 * s) * IN_DIM + i0 + tx] = f2bf(tile[tx][ty + 8 * s]);
}

// ============ encoder: lat = x @ We^T + be, bf16 MFMA, fp32 out ============
__global__ __launch_bounds__(256) void encoder_mfma(
    const unsigned short* __restrict__ xb,   // bf16 [B][640]
    const unsigned short* __restrict__ web,  // bf16 [2560][640]
    const float* __restrict__ be,
    float* __restrict__ lat)                 // fp32 [B][2560]
{
  __shared__ unsigned short As[128 * 32];
  __shared__ unsigned short Bs[128 * 32];

  const int t = threadIdx.x, lane = t & 63, wave = t >> 6;
  const int nt = blockIdx.x % (LAT_DIM / 128);
  const int mt = blockIdx.x / (LAT_DIM / 128);
  const int m0 = mt * 128, n0 = nt * 128;
  const int mBase = (wave & 1) * 64, nBase = (wave >> 1) * 64;

  v4f acc[4][4];
#pragma unroll
  for (int mi = 0; mi < 4; ++mi)
#pragma unroll
    for (int ni = 0; ni < 4; ++ni) acc[mi][ni] = (v4f){0.f, 0.f, 0.f, 0.f};

  const int s1 = t, s2 = t + 256;
  const int r1 = s1 >> 2, q1 = s1 & 3, r2 = s2 >> 2, q2 = s2 & 3;
  const unsigned short* gA1 = xb  + (size_t)(m0 + r1) * IN_DIM + q1 * 8;
  const unsigned short* gA2 = xb  + (size_t)(m0 + r2) * IN_DIM + q2 * 8;
  const unsigned short* gB1 = web + (size_t)(n0 + r1) * IN_DIM + q1 * 8;
  const unsigned short* gB2 = web + (size_t)(n0 + r2) * IN_DIM + q2 * 8;
  unsigned short* lA1 = As + s1 * 8;  unsigned short* lA2 = As + s2 * 8;
  unsigned short* lB1 = Bs + s1 * 8;  unsigned short* lB2 = Bs + s2 * 8;

  const int arow = (mBase + (lane & 15)) * 32 + (lane >> 4) * 8;
  const int brow = (nBase + (lane & 15)) * 32 + (lane >> 4) * 8;

  for (int kt = 0; kt < IN_DIM; kt += 32) {
    async_load16(lA1, gA1 + kt);
    async_load16(lA2, gA2 + kt);
    async_load16(lB1, gB1 + kt);
    async_load16(lB2, gB2 + kt);
    __syncthreads();
    v8s a[4], b[4];
#pragma unroll
    for (int mi = 0; mi < 4; ++mi) a[mi] = *(const v8s*)(As + arow + mi * 16 * 32);
#pragma unroll
    for (int ni = 0; ni < 4; ++ni) b[ni] = *(const v8s*)(Bs + brow + ni * 16 * 32);
#pragma unroll
    for (int mi = 0; mi < 4; ++mi)
#pragma unroll
      for (int ni = 0; ni < 4; ++ni)
        acc[mi][ni] = __builtin_amdgcn_mfma_f32_16x16x32_bf16(a[mi], b[ni], acc[mi][ni], 0, 0, 0);
    __syncthreads();
  }

  float bev[4];
#pragma unroll
  for (int ni = 0; ni < 4; ++ni) bev[ni] = be[n0 + nBase + ni * 16 + (lane & 15)];
#pragma unroll
  for (int mi = 0; mi < 4; ++mi) {
    const int grow0 = m0 + mBase + mi * 16 + (lane >> 4) * 4;
#pragma unroll
    for (int ni = 0; ni < 4; ++ni) {
      const int gcol = n0 + nBase + ni * 16 + (lane & 15);
#pragma unroll
      for (int r = 0; r < 4; ++r)
        lat[(size_t)(grow0 + r) * LAT_DIM + gcol] = acc[mi][ni][r] + bev[ni];
    }
  }
}

// ============ topk v4: slim VALU, LDS diet (~5.9KB), zero+scatter write ======
// Same selection semantics: threshold+compact (order now lane-major; all rank
// decisions are value-multiset-based, and exact boundary ties are resolved by
// an explicit lowest-index trim matching jax top_k), exact bit-bisections,
// window recompute with strictly-sequential ascending-k fp32 fma chain.
#define TK_CAP 160
#define TK_WIN 0.012f

__global__ __launch_bounds__(256) void topk2(
    float* __restrict__ lat,            // dense noisy in, sparse out (in place)
    const float* __restrict__ x,        // fp32 [B][640]
    const float* __restrict__ We,       // fp32 [2560][640]
    const float* __restrict__ be,
    float* __restrict__ ws_val, int* __restrict__ ws_idx)
{
  __shared__ float cval[4][TK_CAP];
  __shared__ int   cidx[4][TK_CAP];
  __shared__ int   winl[4][48];

  const int wave = threadIdx.x >> 6, lane = threadIdx.x & 63;
  const size_t row = (size_t)blockIdx.x * 4 + wave;
  float* rowp = lat + row * LAT_DIM;
  const unsigned long long lmask = (1ull << lane) - 1ull;

  // ---- load latent row as float4; warm the x row into L1/L2 (one touch) ----
  v4f v[10];
  const v4f* row4 = (const v4f*)rowp;
#pragma unroll
  for (int j = 0; j < 10; ++j) v[j] = row4[lane + 64 * j];

  float xw = 0.f;
  if (lane < 40) xw = x[row * IN_DIM + lane * 16];
  asm volatile("" :: "v"(xw));   // keep the warm-load alive (no DCE)

  // ---- row RMS -> initial threshold ----
  float ss = 0.f;
#pragma unroll
  for (int j = 0; j < 10; ++j) {
    ss = fmaf(v[j][0], v[j][0], ss);
    ss = fmaf(v[j][1], v[j][1], ss);
    ss = fmaf(v[j][2], v[j][2], ss);
    ss = fmaf(v[j][3], v[j][3], ss);
  }
#pragma unroll
  for (int off = 32; off > 0; off >>= 1) ss += __shfl_xor(ss, off, 64);
  const float sigma = sqrtf(ss * (1.0f / LAT_DIM));
  float T = 1.96f * sigma;

  // ---- threshold search: per-lane counts + one wave reduce per iter ----
  int cnt = 0;
  for (int it = 0; it < 40; ++it) {
    int cl = 0;
#pragma unroll
    for (int j = 0; j < 10; ++j) {
      cl += (v[j][0] > T);
      cl += (v[j][1] > T);
      cl += (v[j][2] > T);
      cl += (v[j][3] > T);
    }
#pragma unroll
    for (int off = 32; off > 0; off >>= 1) cl += __shfl_xor(cl, off, 64);
    cnt = cl;
    if (cnt >= 44 && cnt <= TK_CAP) break;
    T += (cnt < 44) ? (-0.25f * sigma) : (0.10f * sigma);
  }

  // ---- per-lane bitmask compaction (lane-major slot order) ----
  unsigned long long msk = 0ull;
#pragma unroll
  for (int j = 0; j < 10; ++j) {
#pragma unroll
    for (int c = 0; c < 4; ++c)
      if (v[j][c] > T) msk |= 1ull << (4 * j + c);
  }
  const int nc = (int)__popcll(msk);
  int inc = nc;
#pragma unroll
  for (int off = 1; off < 64; off <<= 1) {
    int tt = __shfl_up(inc, off, 64);
    if (lane >= off) inc += tt;
  }
  const int base = inc - nc;
  cnt = __shfl(inc, 63, 64);
  if (cnt > TK_CAP) cnt = TK_CAP;

  {
    unsigned long long mm = msk;
    int p = base;
    while (mm) {
      int b = __builtin_ctzll(mm);
      mm &= mm - 1ull;
      if (p < TK_CAP) {
        cval[wave][p] = v[b >> 2][b & 3];
        cidx[wave][p] = 256 * (b >> 2) + 4 * lane + (b & 3);
      }
      ++p;
    }
  }

  // ---- v[] is dead: zero-store the sparse row now (overlaps with compute) ----
  asm volatile("s_waitcnt vmcnt(0)" ::: "memory");   // loads serviced before overwrite
  {
    v4f z = (v4f){0.f, 0.f, 0.f, 0.f};
    v4f* out4 = (v4f*)rowp;
#pragma unroll
    for (int j = 0; j < 10; ++j) out4[lane + 64 * j] = z;
  }

  // ---- candidates into registers: 3 slots per lane (+ noisy copies) ----
  const int e0 = lane, e1 = lane + 64, e2 = lane + 128;
  float c0 = (e0 < cnt) ? cval[wave][e0] : -3e38f;
  float c1 = (e1 < cnt) ? cval[wave][e1] : -3e38f;
  float c2 = (e2 < cnt) ? cval[wave][e2] : -3e38f;
  int   i0 = (e0 < cnt) ? cidx[wave][e0] : 0;
  int   i1 = (e1 < cnt) ? cidx[wave][e1] : 0;
  int   i2 = (e2 < cnt) ? cidx[wave][e2] : 0;
  const float n0v = c0, n1v = c1, n2v = c2;   // noisy values for the sparse scatter

  // ---- bisect 1: v32 = exact rank-31 noisy value ----
  float mx = fmaxf(fmaxf(c0, c1), c2);
#pragma unroll
  for (int off = 32; off > 0; off >>= 1) mx = fmaxf(mx, __shfl_xor(mx, off, 64));
  unsigned lo_b = __float_as_uint(fmaxf(T, 0.f));
  unsigned hi_b = __float_as_uint(mx);
  while (hi_b - lo_b > 1u) {
    unsigned mid_b = lo_b + ((hi_b - lo_b) >> 1);
    float midf = __uint_as_float(mid_b);
    int n = (int)__popcll(__ballot(c0 > midf)) + (int)__popcll(__ballot(c1 > midf))
          + (int)__popcll(__ballot(c2 > midf));
    if (n >= KSEL) lo_b = mid_b; else hi_b = mid_b;
  }
  const float v32 = __uint_as_float(hi_b);

  // ---- eligibility + window flags from NOISY values ----
  const bool el0 = (e0 < cnt) && (c0 >= v32 - TK_WIN);
  const bool el1 = (e1 < cnt) && (c1 >= v32 - TK_WIN);
  const bool el2 = (e2 < cnt) && (c2 >= v32 - TK_WIN);
  const bool w0  = (e0 < cnt) && (fabsf(c0 - v32) <= TK_WIN);
  const bool w1  = (e1 < cnt) && (fabsf(c1 - v32) <= TK_WIN);
  const bool w2  = (e2 < cnt) && (fabsf(c2 - v32) <= TK_WIN);

  int wbase = 0;
  {
    unsigned long long b = __ballot(w0);
    if (w0) { int p = wbase + (int)__popcll(b & lmask); if (p < 48) winl[wave][p] = e0; }
    wbase += (int)__popcll(b);
    b = __ballot(w1);
    if (w1) { int p = wbase + (int)__popcll(b & lmask); if (p < 48) winl[wave][p] = e1; }
    wbase += (int)__popcll(b);
    b = __ballot(w2);
    if (w2) { int p = wbase + (int)__popcll(b & lmask); if (p < 48) winl[wave][p] = e2; }
    wbase += (int)__popcll(b);
  }
  const int wcnt = wbase < 48 ? wbase : 48;

  // ---- exact recompute: sequential ascending-k fp32 fma chain ----
  // x via broadcast global loads (row is L1/L2-hot from the warm touch).
  if (lane < wcnt) {
    int slot = winl[wave][lane];
    int c = cidx[wave][slot];
    const v4f* w4 = (const v4f*)(We + (size_t)c * IN_DIM);
    const v4f* x4 = (const v4f*)(x + row * IN_DIM);
    float acc = 0.f;
    v4f wv = w4[0];
#pragma unroll 8
    for (int i = 0; i < IN_DIM / 4 - 1; ++i) {
      v4f wn = w4[i + 1];
      v4f xv = x4[i];
      acc = fmaf(xv[0], wv[0], acc);
      acc = fmaf(xv[1], wv[1], acc);
      acc = fmaf(xv[2], wv[2], acc);
      acc = fmaf(xv[3], wv[3], acc);
      wv = wn;
    }
    {
      v4f xv = x4[IN_DIM / 4 - 1];
      acc = fmaf(xv[0], wv[0], acc);
      acc = fmaf(xv[1], wv[1], acc);
      acc = fmaf(xv[2], wv[2], acc);
      acc = fmaf(xv[3], wv[3], acc);
    }
    cval[wave][slot] = acc + be[c];
  }

  // refresh registers with substituted values
  if (e0 < cnt) c0 = cval[wave][e0];
  if (e1 < cnt) c1 = cval[wave][e1];
  if (e2 < cnt) c2 = cval[wave][e2];

  // ---- bisect 2: exact rank-31 among ELIGIBLE with substituted values ----
  const float q0 = el0 ? c0 : -3e38f;
  const float q1 = el1 ? c1 : -3e38f;
  const float q2 = el2 ? c2 : -3e38f;
  float mx2 = fmaxf(fmaxf(q0, q1), q2);
#pragma unroll
  for (int off = 32; off > 0; off >>= 1) mx2 = fmaxf(mx2, __shfl_xor(mx2, off, 64));
  unsigned lo2_b = __float_as_uint(fmaxf(v32 - 3.0f * TK_WIN, 0.f));
  unsigned hi2_b = __float_as_uint(mx2);
  while (hi2_b - lo2_b > 1u) {
    unsigned mid_b = lo2_b + ((hi2_b - lo2_b) >> 1);
    float midf = __uint_as_float(mid_b);
    int n = (int)__popcll(__ballot(q0 > midf)) + (int)__popcll(__ballot(q1 > midf))
          + (int)__popcll(__ballot(q2 > midf));
    if (n >= KSEL) lo2_b = mid_b; else hi2_b = mid_b;
  }
  const float v32x = __uint_as_float(hi2_b);

  // ---- selection: q >= v32x gives >= 32; trim exact-ties by LARGEST index ----
  bool sA = q0 >= v32x, sB = q1 >= v32x, sC = q2 >= v32x;
  int cg = (int)__popcll(__ballot(sA)) + (int)__popcll(__ballot(sB))
         + (int)__popcll(__ballot(sC));
  while (cg > KSEL) {              // rare: exact ties at the boundary
    int mi3 = -1;
    if (sA && q0 == v32x) mi3 = i0;
    if (sB && q1 == v32x && i1 > mi3) mi3 = i1;
    if (sC && q2 == v32x && i2 > mi3) mi3 = i2;
#pragma unroll
    for (int off = 32; off > 0; off >>= 1) {
      int o = __shfl_xor(mi3, off, 64);
      mi3 = o > mi3 ? o : mi3;
    }
    if      (sA && q0 == v32x && i0 == mi3) sA = false;
    else if (sB && q1 == v32x && i1 == mi3) sB = false;
    else if (sC && q2 == v32x && i2 == mi3) sC = false;
    --cg;
  }

  // ---- write ws in slot-compacted order (exactly 32 selected) ----
  {
    int sbase = 0;
    unsigned long long b = __ballot(sA);
    if (sA) { int p = sbase + (int)__popcll(b & lmask);
      ws_val[row * KSEL + p] = c0; ws_idx[row * KSEL + p] = i0; }
    sbase += (int)__popcll(b);
    b = __ballot(sB);
    if (sB) { int p = sbase + (int)__popcll(b & lmask);
      ws_val[row * KSEL + p] = c1; ws_idx[row * KSEL + p] = i1; }
    sbase += (int)__popcll(b);
    b = __ballot(sC);
    if (sC) { int p = sbase + (int)__popcll(b & lmask);
      ws_val[row * KSEL + p] = c2; ws_idx[row * KSEL + p] = i2; }
  }

  // ---- scatter noisy values over the zeroed row (ordered by vmcnt fence) ----
  asm volatile("s_waitcnt vmcnt(0)" ::: "memory");
  if (sA) rowp[i0] = n0v;
  if (sB) rowp[i1] = n1v;
  if (sC) rowp[i2] = n2v;
}

// ============ decoder: recon = sparse @ Wd^T + bd (bf16 WdT gather) ============
__global__ __launch_bounds__(256) void decoder_kernel(
    const float* __restrict__ ws_val,
    const int*   __restrict__ ws_idx,
    const unsigned short* __restrict__ WdT,
    const float* __restrict__ bd,
    float* __restrict__ recon)
{
  const int wave = threadIdx.x >> 6, lane = threadIdx.x & 63;
  const size_t row = (size_t)blockIdx.x * 4 + wave;

  float myv = 0.f; int myi = 0;
  if (lane < KSEL) { myv = ws_val[row * KSEL + lane]; myi = ws_idx[row * KSEL + lane]; }

  float2 acc[5];
#pragma unroll
  for (int u = 0; u < 5; ++u) acc[u] = *(const float2*)(bd + 2 * lane + 128 * u);

#pragma unroll 4
  for (int j = 0; j < KSEL; ++j) {
    float vj = __shfl(myv, j, 64);
    int   ij = __shfl(myi, j, 64);
    const unsigned short* wr = WdT + (size_t)ij * IN_DIM;
#pragma unroll
    for (int u = 0; u < 5; ++u) {
      unsigned int w2 = *(const unsigned int*)(wr + 2 * lane + 128 * u);
      acc[u].x += vj * __uint_as_float(w2 << 16);
      acc[u].y += vj * __uint_as_float(w2 & 0xffff0000u);
    }
  }
#pragma unroll
  for (int u = 0; u < 5; ++u)
    *(float2*)(recon + row * IN_DIM + 2 * lane + 128 * u) = acc[u];
}

// ============ launch ============
extern "C" void kernel_launch(void* const* d_in, const int* in_sizes, int n_in,
                              void* d_out, int out_size, void* d_ws, size_t ws_size,
                              hipStream_t stream) {
  const float* x  = (const float*)d_in[0];
  const float* We = (const float*)d_in[1];
  const float* be = (const float*)d_in[2];
  const float* Wd = (const float*)d_in[3];
  const float* bd = (const float*)d_in[4];

  float* recon  = (float*)d_out;
  float* sparse = (float*)d_out + (size_t)BATCH * IN_DIM;   // also dense-latent scratch

  char* ws = (char*)d_ws;
  float*          ws_val = (float*)ws;                                   ws += (size_t)BATCH * KSEL * 4;
  int*            ws_idx = (int*)ws;                                     ws += (size_t)BATCH * KSEL * 4;
  unsigned short* WdT    = (unsigned short*)ws;                          ws += (size_t)LAT_DIM * IN_DIM * 2;
  unsigned short* x_bf   = (unsigned short*)ws;                          ws += (size_t)BATCH * IN_DIM * 2;
  unsigned short* We_bf  = (unsigned short*)ws;

  conv_bf16    <<<(BATCH * IN_DIM / 8 + 255) / 256, 256, 0, stream>>>(x, x_bf, BATCH * IN_DIM / 8);
  conv_bf16    <<<(LAT_DIM * IN_DIM / 8 + 255) / 256, 256, 0, stream>>>(We, We_bf, LAT_DIM * IN_DIM / 8);
  transpose_wd <<<(LAT_DIM / 32) * (IN_DIM / 32), 256, 0, stream>>>(Wd, WdT);
  encoder_mfma <<<(BATCH / 128) * (LAT_DIM / 128), 256, 0, stream>>>(x_bf, We_bf, be, sparse);
  topk2        <<<BATCH / 4, 256, 0, stream>>>(sparse, x, We, be, ws_val, ws_idx);
  decoder_kernel<<<BATCH / 4, 256, 0, stream>>>(ws_val, ws_idx, WdT, bd, recon);
}

// Round 4
// 2192.557 us; speedup vs baseline: 1.0215x; 1.0215x over previous
//
#include <hip/hip_runtime.h>
#include <cstdint>

#define BATCH   65536
#define IN_DIM  640
#define LAT_DIM 2560
#define KSEL    32

typedef short  v8s __attribute__((ext_vector_type(8)));
typedef float  v4f __attribute__((ext_vector_type(4)));

__device__ inline void async_load16(void* lds, const void* g) {
  __builtin_amdgcn_global_load_lds(
      (const __attribute__((address_space(1))) unsigned int*)g,
      (__attribute__((address_space(3))) unsigned int*)lds, 16, 0, 0);
}

__device__ inline unsigned short f2bf(float v) {
  unsigned int b = __float_as_uint(v);
  return (unsigned short)((b + 0x7fffu + ((b >> 16) & 1u)) >> 16);
}

// ============ conv fp32 -> bf16, 8 elems/thread ============
__global__ __launch_bounds__(256) void conv_bf16(
    const float* __restrict__ src, unsigned short* __restrict__ dst, int n8)
{
  int i = blockIdx.x * 256 + threadIdx.x;
  if (i >= n8) return;
  const float4* s4 = (const float4*)(src) + i * 2;
  float4 a = s4[0], b = s4[1];
  ushort4 lo = make_ushort4(f2bf(a.x), f2bf(a.y), f2bf(a.z), f2bf(a.w));
  ushort4 hi = make_ushort4(f2bf(b.x), f2bf(b.y), f2bf(b.z), f2bf(b.w));
  *(ushort4*)(dst + (size_t)i * 8)     = lo;
  *(ushort4*)(dst + (size_t)i * 8 + 4) = hi;
}

// ============ transpose Wd [640][2560] -> WdT bf16 [2560][640] ============
__global__ __launch_bounds__(256) void transpose_wd(
    const float* __restrict__ Wd, unsigned short* __restrict__ WdT)
{
  __shared__ float tile[32][33];
  const int tx = threadIdx.x & 31;
  const int ty = threadIdx.x >> 5;
  const int l0 = (blockIdx.x % (LAT_DIM / 32)) * 32;
  const int i0 = (blockIdx.x / (LAT_DIM / 32)) * 32;
#pragma unroll
  for (int s = 0; s < 4; ++s)
    tile[ty + 8 * s][tx] = Wd[(size_t)(i0 + ty + 8 * s) * LAT_DIM + l0 + tx];
  __syncthreads();
#pragma unroll
  for (int s = 0; s < 4; ++s)
    WdT[(size_t)(l0 + ty + 8 * s) * IN_DIM + i0 + tx] = f2bf(tile[tx][ty + 8 * s]);
}

// ============ encoder: lat = x @ We^T + be, bf16 MFMA, fp32 out ============
__global__ __launch_bounds__(256) void encoder_mfma(
    const unsigned short* __restrict__ xb,   // bf16 [B][640]
    const unsigned short* __restrict__ web,  // bf16 [2560][640]
    const float* __restrict__ be,
    float* __restrict__ lat)                 // fp32 [B][2560]
{
  __shared__ unsigned short As[128 * 32];
  __shared__ unsigned short Bs[128 * 32];

  const int t = threadIdx.x, lane = t & 63, wave = t >> 6;
  const int nt = blockIdx.x % (LAT_DIM / 128);
  const int mt = blockIdx.x / (LAT_DIM / 128);
  const int m0 = mt * 128, n0 = nt * 128;
  const int mBase = (wave & 1) * 64, nBase = (wave >> 1) * 64;

  v4f acc[4][4];
#pragma unroll
  for (int mi = 0; mi < 4; ++mi)
#pragma unroll
    for (int ni = 0; ni < 4; ++ni) acc[mi][ni] = (v4f){0.f, 0.f, 0.f, 0.f};

  const int s1 = t, s2 = t + 256;
  const int r1 = s1 >> 2, q1 = s1 & 3, r2 = s2 >> 2, q2 = s2 & 3;
  const unsigned short* gA1 = xb  + (size_t)(m0 + r1) * IN_DIM + q1 * 8;
  const unsigned short* gA2 = xb  + (size_t)(m0 + r2) * IN_DIM + q2 * 8;
  const unsigned short* gB1 = web + (size_t)(n0 + r1) * IN_DIM + q1 * 8;
  const unsigned short* gB2 = web + (size_t)(n0 + r2) * IN_DIM + q2 * 8;
  unsigned short* lA1 = As + s1 * 8;  unsigned short* lA2 = As + s2 * 8;
  unsigned short* lB1 = Bs + s1 * 8;  unsigned short* lB2 = Bs + s2 * 8;

  const int arow = (mBase + (lane & 15)) * 32 + (lane >> 4) * 8;
  const int brow = (nBase + (lane & 15)) * 32 + (lane >> 4) * 8;

  for (int kt = 0; kt < IN_DIM; kt += 32) {
    async_load16(lA1, gA1 + kt);
    async_load16(lA2, gA2 + kt);
    async_load16(lB1, gB1 + kt);
    async_load16(lB2, gB2 + kt);
    __syncthreads();
    v8s a[4], b[4];
#pragma unroll
    for (int mi = 0; mi < 4; ++mi) a[mi] = *(const v8s*)(As + arow + mi * 16 * 32);
#pragma unroll
    for (int ni = 0; ni < 4; ++ni) b[ni] = *(const v8s*)(Bs + brow + ni * 16 * 32);
#pragma unroll
    for (int mi = 0; mi < 4; ++mi)
#pragma unroll
      for (int ni = 0; ni < 4; ++ni)
        acc[mi][ni] = __builtin_amdgcn_mfma_f32_16x16x32_bf16(a[mi], b[ni], acc[mi][ni], 0, 0, 0);
    __syncthreads();
  }

  float bev[4];
#pragma unroll
  for (int ni = 0; ni < 4; ++ni) bev[ni] = be[n0 + nBase + ni * 16 + (lane & 15)];
#pragma unroll
  for (int mi = 0; mi < 4; ++mi) {
    const int grow0 = m0 + mBase + mi * 16 + (lane >> 4) * 4;
#pragma unroll
    for (int ni = 0; ni < 4; ++ni) {
      const int gcol = n0 + nBase + ni * 16 + (lane & 15);
#pragma unroll
      for (int r = 0; r < 4; ++r)
        lat[(size_t)(grow0 + r) * LAT_DIM + gcol] = acc[mi][ni][r] + bev[ni];
    }
  }
}

// ============ topk v5: R3's slim VALU + R2's single-pass masked row write ====
// Selection semantics as v3/v4: threshold+compact (lane-major slot order; rank
// decisions are value-multiset-based, exact boundary ties trimmed by largest
// index = jax lowest-index keep), exact bit-bisections, window recompute with
// strictly-sequential ascending-k fp32 fma chain.
#define TK_CAP 160
#define TK_WIN 0.012f

__global__ __launch_bounds__(256) void topk2(
    float* __restrict__ lat,            // dense noisy in, sparse out (in place)
    const float* __restrict__ x,        // fp32 [B][640]
    const float* __restrict__ We,       // fp32 [2560][640]
    const float* __restrict__ be,
    float* __restrict__ ws_val, int* __restrict__ ws_idx)
{
  __shared__ float cval[4][TK_CAP];
  __shared__ int   cidx[4][TK_CAP];
  __shared__ int   winl[4][48];
  __shared__ int   seli[4][KSEL];

  const int wave = threadIdx.x >> 6, lane = threadIdx.x & 63;
  const size_t row = (size_t)blockIdx.x * 4 + wave;
  float* rowp = lat + row * LAT_DIM;
  const unsigned long long lmask = (1ull << lane) - 1ull;

  // ---- load latent row as float4 (kept live for the final masked write) ----
  v4f v[10];
  const v4f* row4 = (const v4f*)rowp;
#pragma unroll
  for (int j = 0; j < 10; ++j) v[j] = row4[lane + 64 * j];

  // warm the x row into L1/L2 (one line per active lane)
  float xw = 0.f;
  if (lane < 40) xw = x[row * IN_DIM + lane * 16];
  asm volatile("" :: "v"(xw));   // keep alive (no DCE)

  // ---- row RMS -> initial threshold ----
  float ss = 0.f;
#pragma unroll
  for (int j = 0; j < 10; ++j) {
    ss = fmaf(v[j][0], v[j][0], ss);
    ss = fmaf(v[j][1], v[j][1], ss);
    ss = fmaf(v[j][2], v[j][2], ss);
    ss = fmaf(v[j][3], v[j][3], ss);
  }
#pragma unroll
  for (int off = 32; off > 0; off >>= 1) ss += __shfl_xor(ss, off, 64);
  const float sigma = sqrtf(ss * (1.0f / LAT_DIM));
  float T = 1.96f * sigma;

  // ---- threshold search: per-lane counts + one wave reduce per iter ----
  int cnt = 0;
  for (int it = 0; it < 40; ++it) {
    int cl = 0;
#pragma unroll
    for (int j = 0; j < 10; ++j) {
      cl += (v[j][0] > T);
      cl += (v[j][1] > T);
      cl += (v[j][2] > T);
      cl += (v[j][3] > T);
    }
#pragma unroll
    for (int off = 32; off > 0; off >>= 1) cl += __shfl_xor(cl, off, 64);
    cnt = cl;
    if (cnt >= 44 && cnt <= TK_CAP) break;
    T += (cnt < 44) ? (-0.25f * sigma) : (0.10f * sigma);
  }

  // ---- per-lane bitmask compaction (lane-major slot order) ----
  unsigned long long msk = 0ull;
#pragma unroll
  for (int j = 0; j < 10; ++j) {
#pragma unroll
    for (int c = 0; c < 4; ++c)
      if (v[j][c] > T) msk |= 1ull << (4 * j + c);
  }
  const int nc = (int)__popcll(msk);
  int inc = nc;
#pragma unroll
  for (int off = 1; off < 64; off <<= 1) {
    int tt = __shfl_up(inc, off, 64);
    if (lane >= off) inc += tt;
  }
  const int base = inc - nc;
  cnt = __shfl(inc, 63, 64);
  if (cnt > TK_CAP) cnt = TK_CAP;

  {
    unsigned long long mm = msk;
    int p = base;
    while (mm) {
      int b = __builtin_ctzll(mm);
      mm &= mm - 1ull;
      if (p < TK_CAP) {
        cval[wave][p] = v[b >> 2][b & 3];
        cidx[wave][p] = 256 * (b >> 2) + 4 * lane + (b & 3);
      }
      ++p;
    }
  }

  // ---- candidates into registers: 3 slots per lane ----
  const int e0 = lane, e1 = lane + 64, e2 = lane + 128;
  float c0 = (e0 < cnt) ? cval[wave][e0] : -3e38f;
  float c1 = (e1 < cnt) ? cval[wave][e1] : -3e38f;
  float c2 = (e2 < cnt) ? cval[wave][e2] : -3e38f;
  int   i0 = (e0 < cnt) ? cidx[wave][e0] : 0;
  int   i1 = (e1 < cnt) ? cidx[wave][e1] : 0;
  int   i2 = (e2 < cnt) ? cidx[wave][e2] : 0;

  // ---- bisect 1: v32 = exact rank-31 noisy value ----
  float mx = fmaxf(fmaxf(c0, c1), c2);
#pragma unroll
  for (int off = 32; off > 0; off >>= 1) mx = fmaxf(mx, __shfl_xor(mx, off, 64));
  unsigned lo_b = __float_as_uint(fmaxf(T, 0.f));
  unsigned hi_b = __float_as_uint(mx);
  while (hi_b - lo_b > 1u) {
    unsigned mid_b = lo_b + ((hi_b - lo_b) >> 1);
    float midf = __uint_as_float(mid_b);
    int n = (int)__popcll(__ballot(c0 > midf)) + (int)__popcll(__ballot(c1 > midf))
          + (int)__popcll(__ballot(c2 > midf));
    if (n >= KSEL) lo_b = mid_b; else hi_b = mid_b;
  }
  const float v32 = __uint_as_float(hi_b);

  // ---- eligibility + window flags from NOISY values ----
  const bool el0 = (e0 < cnt) && (c0 >= v32 - TK_WIN);
  const bool el1 = (e1 < cnt) && (c1 >= v32 - TK_WIN);
  const bool el2 = (e2 < cnt) && (c2 >= v32 - TK_WIN);
  const bool w0  = (e0 < cnt) && (fabsf(c0 - v32) <= TK_WIN);
  const bool w1  = (e1 < cnt) && (fabsf(c1 - v32) <= TK_WIN);
  const bool w2  = (e2 < cnt) && (fabsf(c2 - v32) <= TK_WIN);

  int wbase = 0;
  {
    unsigned long long b = __ballot(w0);
    if (w0) { int p = wbase + (int)__popcll(b & lmask); if (p < 48) winl[wave][p] = e0; }
    wbase += (int)__popcll(b);
    b = __ballot(w1);
    if (w1) { int p = wbase + (int)__popcll(b & lmask); if (p < 48) winl[wave][p] = e1; }
    wbase += (int)__popcll(b);
    b = __ballot(w2);
    if (w2) { int p = wbase + (int)__popcll(b & lmask); if (p < 48) winl[wave][p] = e2; }
    wbase += (int)__popcll(b);
  }
  const int wcnt = wbase < 48 ? wbase : 48;

  // ---- exact recompute: sequential ascending-k fp32 fma chain ----
  // x via broadcast global loads (row is L1/L2-hot from the warm touch).
  if (lane < wcnt) {
    int slot = winl[wave][lane];
    int c = cidx[wave][slot];
    const v4f* w4 = (const v4f*)(We + (size_t)c * IN_DIM);
    const v4f* x4 = (const v4f*)(x + row * IN_DIM);
    float acc = 0.f;
    v4f wv = w4[0];
#pragma unroll 8
    for (int i = 0; i < IN_DIM / 4 - 1; ++i) {
      v4f wn = w4[i + 1];
      v4f xv = x4[i];
      acc = fmaf(xv[0], wv[0], acc);
      acc = fmaf(xv[1], wv[1], acc);
      acc = fmaf(xv[2], wv[2], acc);
      acc = fmaf(xv[3], wv[3], acc);
      wv = wn;
    }
    {
      v4f xv = x4[IN_DIM / 4 - 1];
      acc = fmaf(xv[0], wv[0], acc);
      acc = fmaf(xv[1], wv[1], acc);
      acc = fmaf(xv[2], wv[2], acc);
      acc = fmaf(xv[3], wv[3], acc);
    }
    cval[wave][slot] = acc + be[c];
  }

  // refresh registers with substituted values
  if (e0 < cnt) c0 = cval[wave][e0];
  if (e1 < cnt) c1 = cval[wave][e1];
  if (e2 < cnt) c2 = cval[wave][e2];

  // ---- bisect 2: exact rank-31 among ELIGIBLE with substituted values ----
  const float q0 = el0 ? c0 : -3e38f;
  const float q1 = el1 ? c1 : -3e38f;
  const float q2 = el2 ? c2 : -3e38f;
  float mx2 = fmaxf(fmaxf(q0, q1), q2);
#pragma unroll
  for (int off = 32; off > 0; off >>= 1) mx2 = fmaxf(mx2, __shfl_xor(mx2, off, 64));
  unsigned lo2_b = __float_as_uint(fmaxf(v32 - 3.0f * TK_WIN, 0.f));
  unsigned hi2_b = __float_as_uint(mx2);
  while (hi2_b - lo2_b > 1u) {
    unsigned mid_b = lo2_b + ((hi2_b - lo2_b) >> 1);
    float midf = __uint_as_float(mid_b);
    int n = (int)__popcll(__ballot(q0 > midf)) + (int)__popcll(__ballot(q1 > midf))
          + (int)__popcll(__ballot(q2 > midf));
    if (n >= KSEL) lo2_b = mid_b; else hi2_b = mid_b;
  }
  const float v32x = __uint_as_float(hi2_b);

  // ---- selection: q >= v32x gives >= 32; trim exact-ties by LARGEST index ----
  bool sA = q0 >= v32x, sB = q1 >= v32x, sC = q2 >= v32x;
  int cg = (int)__popcll(__ballot(sA)) + (int)__popcll(__ballot(sB))
         + (int)__popcll(__ballot(sC));
  while (cg > KSEL) {              // rare: exact ties at the boundary
    int mi3 = -1;
    if (sA && q0 == v32x) mi3 = i0;
    if (sB && q1 == v32x && i1 > mi3) mi3 = i1;
    if (sC && q2 == v32x && i2 > mi3) mi3 = i2;
#pragma unroll
    for (int off = 32; off > 0; off >>= 1) {
      int o = __shfl_xor(mi3, off, 64);
      mi3 = o > mi3 ? o : mi3;
    }
    if      (sA && q0 == v32x && i0 == mi3) sA = false;
    else if (sB && q1 == v32x && i1 == mi3) sB = false;
    else if (sC && q2 == v32x && i2 == mi3) sC = false;
    --cg;
  }

  // ---- write ws + seli in slot-compacted order (exactly 32 selected) ----
  {
    int sbase = 0;
    unsigned long long b = __ballot(sA);
    if (sA) { int p = sbase + (int)__popcll(b & lmask);
      ws_val[row * KSEL + p] = c0; ws_idx[row * KSEL + p] = i0; seli[wave][p] = i0; }
    sbase += (int)__popcll(b);
    b = __ballot(sB);
    if (sB) { int p = sbase + (int)__popcll(b & lmask);
      ws_val[row * KSEL + p] = c1; ws_idx[row * KSEL + p] = i1; seli[wave][p] = i1; }
    sbase += (int)__popcll(b);
    b = __ballot(sC);
    if (sC) { int p = sbase + (int)__popcll(b & lmask);
      ws_val[row * KSEL + p] = c2; ws_idx[row * KSEL + p] = i2; seli[wave][p] = i2; }
  }

  // ---- rebuild per-lane float4 mask from seli, masked single-pass write ----
  // element e = 256j + 4l + c: owner lane = (e>>2)&63, bit = (e>>8)*4 + (e&3)
  unsigned long long m = 0ull;
#pragma unroll
  for (int s = 0; s < KSEL; ++s) {
    int idx = seli[wave][s];
    if (((idx >> 2) & 63) == lane) m |= 1ull << ((idx >> 8) * 4 + (idx & 3));
  }
  v4f* out4 = (v4f*)rowp;
#pragma unroll
  for (int j = 0; j < 10; ++j) {
    v4f o;
    o[0] = ((m >> (4 * j + 0)) & 1ull) ? v[j][0] : 0.f;
    o[1] = ((m >> (4 * j + 1)) & 1ull) ? v[j][1] : 0.f;
    o[2] = ((m >> (4 * j + 2)) & 1ull) ? v[j][2] : 0.f;
    o[3] = ((m >> (4 * j + 3)) & 1ull) ? v[j][3] : 0.f;
    out4[lane + 64 * j] = o;
  }
}

// ============ decoder: recon = sparse @ Wd^T + bd (bf16 WdT gather) ============
__global__ __launch_bounds__(256) void decoder_kernel(
    const float* __restrict__ ws_val,
    const int*   __restrict__ ws_idx,
    const unsigned short* __restrict__ WdT,
    const float* __restrict__ bd,
    float* __restrict__ recon)
{
  const int wave = threadIdx.x >> 6, lane = threadIdx.x & 63;
  const size_t row = (size_t)blockIdx.x * 4 + wave;

  float myv = 0.f; int myi = 0;
  if (lane < KSEL) { myv = ws_val[row * KSEL + lane]; myi = ws_idx[row * KSEL + lane]; }

  float2 acc[5];
#pragma unroll
  for (int u = 0; u < 5; ++u) acc[u] = *(const float2*)(bd + 2 * lane + 128 * u);

#pragma unroll 4
  for (int j = 0; j < KSEL; ++j) {
    float vj = __shfl(myv, j, 64);
    int   ij = __shfl(myi, j, 64);
    const unsigned short* wr = WdT + (size_t)ij * IN_DIM;
#pragma unroll
    for (int u = 0; u < 5; ++u) {
      unsigned int w2 = *(const unsigned int*)(wr + 2 * lane + 128 * u);
      acc[u].x += vj * __uint_as_float(w2 << 16);
      acc[u].y += vj * __uint_as_float(w2 & 0xffff0000u);
    }
  }
#pragma unroll
  for (int u = 0; u < 5; ++u)
    *(float2*)(recon + row * IN_DIM + 2 * lane + 128 * u) = acc[u];
}

// ============ launch ============
extern "C" void kernel_launch(void* const* d_in, const int* in_sizes, int n_in,
                              void* d_out, int out_size, void* d_ws, size_t ws_size,
                              hipStream_t stream) {
  const float* x  = (const float*)d_in[0];
  const float* We = (const float*)d_in[1];
  const float* be = (const float*)d_in[2];
  const float* Wd = (const float*)d_in[3];
  const float* bd = (const float*)d_in[4];

  float* recon  = (float*)d_out;
  float* sparse = (float*)d_out + (size_t)BATCH * IN_DIM;   // also dense-latent scratch

  char* ws = (char*)d_ws;
  float*          ws_val = (float*)ws;                                   ws += (size_t)BATCH * KSEL * 4;
  int*            ws_idx = (int*)ws;                                     ws += (size_t)BATCH * KSEL * 4;
  unsigned short* WdT    = (unsigned short*)ws;                          ws += (size_t)LAT_DIM * IN_DIM * 2;
  unsigned short* x_bf   = (unsigned short*)ws;                          ws += (size_t)BATCH * IN_DIM * 2;
  unsigned short* We_bf  = (unsigned short*)ws;

  conv_bf16    <<<(BATCH * IN_DIM / 8 + 255) / 256, 256, 0, stream>>>(x, x_bf, BATCH * IN_DIM / 8);
  conv_bf16    <<<(LAT_DIM * IN_DIM / 8 + 255) / 256, 256, 0, stream>>>(We, We_bf, LAT_DIM * IN_DIM / 8);
  transpose_wd <<<(LAT_DIM / 32) * (IN_DIM / 32), 256, 0, stream>>>(Wd, WdT);
  encoder_mfma <<<(BATCH / 128) * (LAT_DIM / 128), 256, 0, stream>>>(x_bf, We_bf, be, sparse);
  topk2        <<<BATCH / 4, 256, 0, stream>>>(sparse, x, We, be, ws_val, ws_idx);
  decoder_kernel<<<BATCH / 4, 256, 0, stream>>>(ws_val, ws_idx, WdT, bd, recon);
}

// Round 5
// 2057.428 us; speedup vs baseline: 1.0886x; 1.0657x over previous
//
#include <hip/hip_runtime.h>
#include <cstdint>

#define BATCH   65536
#define IN_DIM  640
#define LAT_DIM 2560
#define KSEL    32

typedef short  v8s __attribute__((ext_vector_type(8)));
typedef float  v4f __attribute__((ext_vector_type(4)));

__device__ inline void async_load16(void* lds, const void* g) {
  __builtin_amdgcn_global_load_lds(
      (const __attribute__((address_space(1))) unsigned int*)g,
      (__attribute__((address_space(3))) unsigned int*)lds, 16, 0, 0);
}

__device__ inline unsigned short f2bf(float v) {
  unsigned int b = __float_as_uint(v);
  return (unsigned short)((b + 0x7fffu + ((b >> 16) & 1u)) >> 16);
}

// ============ conv fp32 -> bf16, 8 elems/thread ============
__global__ __launch_bounds__(256) void conv_bf16(
    const float* __restrict__ src, unsigned short* __restrict__ dst, int n8)
{
  int i = blockIdx.x * 256 + threadIdx.x;
  if (i >= n8) return;
  const float4* s4 = (const float4*)(src) + i * 2;
  float4 a = s4[0], b = s4[1];
  ushort4 lo = make_ushort4(f2bf(a.x), f2bf(a.y), f2bf(a.z), f2bf(a.w));
  ushort4 hi = make_ushort4(f2bf(b.x), f2bf(b.y), f2bf(b.z), f2bf(b.w));
  *(ushort4*)(dst + (size_t)i * 8)     = lo;
  *(ushort4*)(dst + (size_t)i * 8 + 4) = hi;
}

// ============ transpose Wd [640][2560] -> WdT bf16 [2560][640] ============
__global__ __launch_bounds__(256) void transpose_wd(
    const float* __restrict__ Wd, unsigned short* __restrict__ WdT)
{
  __shared__ float tile[32][33];
  const int tx = threadIdx.x & 31;
  const int ty = threadIdx.x >> 5;
  const int l0 = (blockIdx.x % (LAT_DIM / 32)) * 32;
  const int i0 = (blockIdx.x / (LAT_DIM / 32)) * 32;
#pragma unroll
  for (int s = 0; s < 4; ++s)
    tile[ty + 8 * s][tx] = Wd[(size_t)(i0 + ty + 8 * s) * LAT_DIM + l0 + tx];
  __syncthreads();
#pragma unroll
  for (int s = 0; s < 4; ++s)
    WdT[(size_t)(l0 + ty + 8 * s) * IN_DIM + i0 + tx] = f2bf(tile[tx][ty + 8 * s]);
}

// ============ encoder: lat = x @ We^T + be, bf16 MFMA, fp32 out ============
__global__ __launch_bounds__(256) void encoder_mfma(
    const unsigned short* __restrict__ xb,   // bf16 [B][640]
    const unsigned short* __restrict__ web,  // bf16 [2560][640]
    const float* __restrict__ be,
    float* __restrict__ lat)                 // fp32 [B][2560]
{
  __shared__ unsigned short As[128 * 32];
  __shared__ unsigned short Bs[128 * 32];

  const int t = threadIdx.x, lane = t & 63, wave = t >> 6;
  const int nt = blockIdx.x % (LAT_DIM / 128);
  const int mt = blockIdx.x / (LAT_DIM / 128);
  const int m0 = mt * 128, n0 = nt * 128;
  const int mBase = (wave & 1) * 64, nBase = (wave >> 1) * 64;

  v4f acc[4][4];
#pragma unroll
  for (int mi = 0; mi < 4; ++mi)
#pragma unroll
    for (int ni = 0; ni < 4; ++ni) acc[mi][ni] = (v4f){0.f, 0.f, 0.f, 0.f};

  const int s1 = t, s2 = t + 256;
  const int r1 = s1 >> 2, q1 = s1 & 3, r2 = s2 >> 2, q2 = s2 & 3;
  const unsigned short* gA1 = xb  + (size_t)(m0 + r1) * IN_DIM + q1 * 8;
  const unsigned short* gA2 = xb  + (size_t)(m0 + r2) * IN_DIM + q2 * 8;
  const unsigned short* gB1 = web + (size_t)(n0 + r1) * IN_DIM + q1 * 8;
  const unsigned short* gB2 = web + (size_t)(n0 + r2) * IN_DIM + q2 * 8;
  unsigned short* lA1 = As + s1 * 8;  unsigned short* lA2 = As + s2 * 8;
  unsigned short* lB1 = Bs + s1 * 8;  unsigned short* lB2 = Bs + s2 * 8;

  const int arow = (mBase + (lane & 15)) * 32 + (lane >> 4) * 8;
  const int brow = (nBase + (lane & 15)) * 32 + (lane >> 4) * 8;

  for (int kt = 0; kt < IN_DIM; kt += 32) {
    async_load16(lA1, gA1 + kt);
    async_load16(lA2, gA2 + kt);
    async_load16(lB1, gB1 + kt);
    async_load16(lB2, gB2 + kt);
    __syncthreads();
    v8s a[4], b[4];
#pragma unroll
    for (int mi = 0; mi < 4; ++mi) a[mi] = *(const v8s*)(As + arow + mi * 16 * 32);
#pragma unroll
    for (int ni = 0; ni < 4; ++ni) b[ni] = *(const v8s*)(Bs + brow + ni * 16 * 32);
#pragma unroll
    for (int mi = 0; mi < 4; ++mi)
#pragma unroll
      for (int ni = 0; ni < 4; ++ni)
        acc[mi][ni] = __builtin_amdgcn_mfma_f32_16x16x32_bf16(a[mi], b[ni], acc[mi][ni], 0, 0, 0);
    __syncthreads();
  }

  float bev[4];
#pragma unroll
  for (int ni = 0; ni < 4; ++ni) bev[ni] = be[n0 + nBase + ni * 16 + (lane & 15)];
#pragma unroll
  for (int mi = 0; mi < 4; ++mi) {
    const int grow0 = m0 + mBase + mi * 16 + (lane >> 4) * 4;
#pragma unroll
    for (int ni = 0; ni < 4; ++ni) {
      const int gcol = n0 + nBase + ni * 16 + (lane & 15);
#pragma unroll
      for (int r = 0; r < 4; ++r)
        lat[(size_t)(grow0 + r) * LAT_DIM + gcol] = acc[mi][ni][r] + bev[ni];
    }
  }
}

// ============ topk v6: v5 with COMPILE-TIME-indexed compaction (no scratch) ==
// R4's regression was rule-#20 scratch spill: v[b>>2][b&3] with runtime b
// forced v[] into local memory (+655MB write, +280MB fetch per pass). Here the
// compaction unrolls j,c statically and derives the slot from prefix-popcount
// of the per-lane bitmask; identical slots/order/values, zero runtime indexing
// of registers. Everything else identical to v5.
#define TK_CAP 160
#define TK_WIN 0.012f

__global__ __launch_bounds__(256) void topk2(
    float* __restrict__ lat,            // dense noisy in, sparse out (in place)
    const float* __restrict__ x,        // fp32 [B][640]
    const float* __restrict__ We,       // fp32 [2560][640]
    const float* __restrict__ be,
    float* __restrict__ ws_val, int* __restrict__ ws_idx)
{
  __shared__ float cval[4][TK_CAP];
  __shared__ int   cidx[4][TK_CAP];
  __shared__ int   winl[4][48];
  __shared__ int   seli[4][KSEL];

  const int wave = threadIdx.x >> 6, lane = threadIdx.x & 63;
  const size_t row = (size_t)blockIdx.x * 4 + wave;
  float* rowp = lat + row * LAT_DIM;
  const unsigned long long lmask = (1ull << lane) - 1ull;

  // ---- load latent row as float4 (kept live for the final masked write) ----
  v4f v[10];
  const v4f* row4 = (const v4f*)rowp;
#pragma unroll
  for (int j = 0; j < 10; ++j) v[j] = row4[lane + 64 * j];

  // warm the x row into L1/L2 (one line per active lane)
  float xw = 0.f;
  if (lane < 40) xw = x[row * IN_DIM + lane * 16];
  asm volatile("" :: "v"(xw));   // keep alive (no DCE)

  // ---- row RMS -> initial threshold ----
  float ss = 0.f;
#pragma unroll
  for (int j = 0; j < 10; ++j) {
    ss = fmaf(v[j][0], v[j][0], ss);
    ss = fmaf(v[j][1], v[j][1], ss);
    ss = fmaf(v[j][2], v[j][2], ss);
    ss = fmaf(v[j][3], v[j][3], ss);
  }
#pragma unroll
  for (int off = 32; off > 0; off >>= 1) ss += __shfl_xor(ss, off, 64);
  const float sigma = sqrtf(ss * (1.0f / LAT_DIM));
  float T = 1.96f * sigma;

  // ---- threshold search: per-lane counts + one wave reduce per iter ----
  int cnt = 0;
  for (int it = 0; it < 40; ++it) {
    int cl = 0;
#pragma unroll
    for (int j = 0; j < 10; ++j) {
      cl += (v[j][0] > T);
      cl += (v[j][1] > T);
      cl += (v[j][2] > T);
      cl += (v[j][3] > T);
    }
#pragma unroll
    for (int off = 32; off > 0; off >>= 1) cl += __shfl_xor(cl, off, 64);
    cnt = cl;
    if (cnt >= 44 && cnt <= TK_CAP) break;
    T += (cnt < 44) ? (-0.25f * sigma) : (0.10f * sigma);
  }

  // ---- per-lane bitmask + prefix-scan for wave-level slot base ----
  unsigned long long msk = 0ull;
#pragma unroll
  for (int j = 0; j < 10; ++j) {
#pragma unroll
    for (int c = 0; c < 4; ++c)
      if (v[j][c] > T) msk |= 1ull << (4 * j + c);
  }
  const int nc = (int)__popcll(msk);
  int inc = nc;
#pragma unroll
  for (int off = 1; off < 64; off <<= 1) {
    int tt = __shfl_up(inc, off, 64);
    if (lane >= off) inc += tt;
  }
  const int base = inc - nc;
  cnt = __shfl(inc, 63, 64);
  if (cnt > TK_CAP) cnt = TK_CAP;

  // ---- compaction with STATIC v[] indexing (slot = base + prefix popcount) --
#pragma unroll
  for (int j = 0; j < 10; ++j) {
#pragma unroll
    for (int c = 0; c < 4; ++c) {
      if (v[j][c] > T) {
        const int bit = 4 * j + c;
        int p = base + (int)__popcll(msk & ((1ull << bit) - 1ull));
        if (p < TK_CAP) {
          cval[wave][p] = v[j][c];
          cidx[wave][p] = 256 * j + 4 * lane + c;
        }
      }
    }
  }

  // ---- candidates into registers: 3 slots per lane ----
  const int e0 = lane, e1 = lane + 64, e2 = lane + 128;
  float c0 = (e0 < cnt) ? cval[wave][e0] : -3e38f;
  float c1 = (e1 < cnt) ? cval[wave][e1] : -3e38f;
  float c2 = (e2 < cnt) ? cval[wave][e2] : -3e38f;
  int   i0 = (e0 < cnt) ? cidx[wave][e0] : 0;
  int   i1 = (e1 < cnt) ? cidx[wave][e1] : 0;
  int   i2 = (e2 < cnt) ? cidx[wave][e2] : 0;

  // ---- bisect 1: v32 = exact rank-31 noisy value ----
  float mx = fmaxf(fmaxf(c0, c1), c2);
#pragma unroll
  for (int off = 32; off > 0; off >>= 1) mx = fmaxf(mx, __shfl_xor(mx, off, 64));
  unsigned lo_b = __float_as_uint(fmaxf(T, 0.f));
  unsigned hi_b = __float_as_uint(mx);
  while (hi_b - lo_b > 1u) {
    unsigned mid_b = lo_b + ((hi_b - lo_b) >> 1);
    float midf = __uint_as_float(mid_b);
    int n = (int)__popcll(__ballot(c0 > midf)) + (int)__popcll(__ballot(c1 > midf))
          + (int)__popcll(__ballot(c2 > midf));
    if (n >= KSEL) lo_b = mid_b; else hi_b = mid_b;
  }
  const float v32 = __uint_as_float(hi_b);

  // ---- eligibility + window flags from NOISY values ----
  const bool el0 = (e0 < cnt) && (c0 >= v32 - TK_WIN);
  const bool el1 = (e1 < cnt) && (c1 >= v32 - TK_WIN);
  const bool el2 = (e2 < cnt) && (c2 >= v32 - TK_WIN);
  const bool w0  = (e0 < cnt) && (fabsf(c0 - v32) <= TK_WIN);
  const bool w1  = (e1 < cnt) && (fabsf(c1 - v32) <= TK_WIN);
  const bool w2  = (e2 < cnt) && (fabsf(c2 - v32) <= TK_WIN);

  int wbase = 0;
  {
    unsigned long long b = __ballot(w0);
    if (w0) { int p = wbase + (int)__popcll(b & lmask); if (p < 48) winl[wave][p] = e0; }
    wbase += (int)__popcll(b);
    b = __ballot(w1);
    if (w1) { int p = wbase + (int)__popcll(b & lmask); if (p < 48) winl[wave][p] = e1; }
    wbase += (int)__popcll(b);
    b = __ballot(w2);
    if (w2) { int p = wbase + (int)__popcll(b & lmask); if (p < 48) winl[wave][p] = e2; }
    wbase += (int)__popcll(b);
  }
  const int wcnt = wbase < 48 ? wbase : 48;

  // ---- exact recompute: sequential ascending-k fp32 fma chain ----
  // x via broadcast global loads (row is L1/L2-hot from the warm touch).
  if (lane < wcnt) {
    int slot = winl[wave][lane];
    int c = cidx[wave][slot];
    const v4f* w4 = (const v4f*)(We + (size_t)c * IN_DIM);
    const v4f* x4 = (const v4f*)(x + row * IN_DIM);
    float acc = 0.f;
    v4f wv = w4[0];
#pragma unroll 8
    for (int i = 0; i < IN_DIM / 4 - 1; ++i) {
      v4f wn = w4[i + 1];
      v4f xv = x4[i];
      acc = fmaf(xv[0], wv[0], acc);
      acc = fmaf(xv[1], wv[1], acc);
      acc = fmaf(xv[2], wv[2], acc);
      acc = fmaf(xv[3], wv[3], acc);
      wv = wn;
    }
    {
      v4f xv = x4[IN_DIM / 4 - 1];
      acc = fmaf(xv[0], wv[0], acc);
      acc = fmaf(xv[1], wv[1], acc);
      acc = fmaf(xv[2], wv[2], acc);
      acc = fmaf(xv[3], wv[3], acc);
    }
    cval[wave][slot] = acc + be[c];
  }

  // refresh registers with substituted values
  if (e0 < cnt) c0 = cval[wave][e0];
  if (e1 < cnt) c1 = cval[wave][e1];
  if (e2 < cnt) c2 = cval[wave][e2];

  // ---- bisect 2: exact rank-31 among ELIGIBLE with substituted values ----
  const float q0 = el0 ? c0 : -3e38f;
  const float q1 = el1 ? c1 : -3e38f;
  const float q2 = el2 ? c2 : -3e38f;
  float mx2 = fmaxf(fmaxf(q0, q1), q2);
#pragma unroll
  for (int off = 32; off > 0; off >>= 1) mx2 = fmaxf(mx2, __shfl_xor(mx2, off, 64));
  unsigned lo2_b = __float_as_uint(fmaxf(v32 - 3.0f * TK_WIN, 0.f));
  unsigned hi2_b = __float_as_uint(mx2);
  while (hi2_b - lo2_b > 1u) {
    unsigned mid_b = lo2_b + ((hi2_b - lo2_b) >> 1);
    float midf = __uint_as_float(mid_b);
    int n = (int)__popcll(__ballot(q0 > midf)) + (int)__popcll(__ballot(q1 > midf))
          + (int)__popcll(__ballot(q2 > midf));
    if (n >= KSEL) lo2_b = mid_b; else hi2_b = mid_b;
  }
  const float v32x = __uint_as_float(hi2_b);

  // ---- selection: q >= v32x gives >= 32; trim exact-ties by LARGEST index ----
  bool sA = q0 >= v32x, sB = q1 >= v32x, sC = q2 >= v32x;
  int cg = (int)__popcll(__ballot(sA)) + (int)__popcll(__ballot(sB))
         + (int)__popcll(__ballot(sC));
  while (cg > KSEL) {              // rare: exact ties at the boundary
    int mi3 = -1;
    if (sA && q0 == v32x) mi3 = i0;
    if (sB && q1 == v32x && i1 > mi3) mi3 = i1;
    if (sC && q2 == v32x && i2 > mi3) mi3 = i2;
#pragma unroll
    for (int off = 32; off > 0; off >>= 1) {
      int o = __shfl_xor(mi3, off, 64);
      mi3 = o > mi3 ? o : mi3;
    }
    if      (sA && q0 == v32x && i0 == mi3) sA = false;
    else if (sB && q1 == v32x && i1 == mi3) sB = false;
    else if (sC && q2 == v32x && i2 == mi3) sC = false;
    --cg;
  }

  // ---- write ws + seli in slot-compacted order (exactly 32 selected) ----
  {
    int sbase = 0;
    unsigned long long b = __ballot(sA);
    if (sA) { int p = sbase + (int)__popcll(b & lmask);
      ws_val[row * KSEL + p] = c0; ws_idx[row * KSEL + p] = i0; seli[wave][p] = i0; }
    sbase += (int)__popcll(b);
    b = __ballot(sB);
    if (sB) { int p = sbase + (int)__popcll(b & lmask);
      ws_val[row * KSEL + p] = c1; ws_idx[row * KSEL + p] = i1; seli[wave][p] = i1; }
    sbase += (int)__popcll(b);
    b = __ballot(sC);
    if (sC) { int p = sbase + (int)__popcll(b & lmask);
      ws_val[row * KSEL + p] = c2; ws_idx[row * KSEL + p] = i2; seli[wave][p] = i2; }
  }

  // ---- rebuild per-lane float4 mask from seli, masked single-pass write ----
  // element e = 256j + 4l + c: owner lane = (e>>2)&63, bit = (e>>8)*4 + (e&3)
  unsigned long long m = 0ull;
#pragma unroll
  for (int s = 0; s < KSEL; ++s) {
    int idx = seli[wave][s];
    if (((idx >> 2) & 63) == lane) m |= 1ull << ((idx >> 8) * 4 + (idx & 3));
  }
  v4f* out4 = (v4f*)rowp;
#pragma unroll
  for (int j = 0; j < 10; ++j) {
    v4f o;
    o[0] = ((m >> (4 * j + 0)) & 1ull) ? v[j][0] : 0.f;
    o[1] = ((m >> (4 * j + 1)) & 1ull) ? v[j][1] : 0.f;
    o[2] = ((m >> (4 * j + 2)) & 1ull) ? v[j][2] : 0.f;
    o[3] = ((m >> (4 * j + 3)) & 1ull) ? v[j][3] : 0.f;
    out4[lane + 64 * j] = o;
  }
}

// ============ decoder: recon = sparse @ Wd^T + bd (bf16 WdT gather) ============
__global__ __launch_bounds__(256) void decoder_kernel(
    const float* __restrict__ ws_val,
    const int*   __restrict__ ws_idx,
    const unsigned short* __restrict__ WdT,
    const float* __restrict__ bd,
    float* __restrict__ recon)
{
  const int wave = threadIdx.x >> 6, lane = threadIdx.x & 63;
  const size_t row = (size_t)blockIdx.x * 4 + wave;

  float myv = 0.f; int myi = 0;
  if (lane < KSEL) { myv = ws_val[row * KSEL + lane]; myi = ws_idx[row * KSEL + lane]; }

  float2 acc[5];
#pragma unroll
  for (int u = 0; u < 5; ++u) acc[u] = *(const float2*)(bd + 2 * lane + 128 * u);

#pragma unroll 4
  for (int j = 0; j < KSEL; ++j) {
    float vj = __shfl(myv, j, 64);
    int   ij = __shfl(myi, j, 64);
    const unsigned short* wr = WdT + (size_t)ij * IN_DIM;
#pragma unroll
    for (int u = 0; u < 5; ++u) {
      unsigned int w2 = *(const unsigned int*)(wr + 2 * lane + 128 * u);
      acc[u].x += vj * __uint_as_float(w2 << 16);
      acc[u].y += vj * __uint_as_float(w2 & 0xffff0000u);
    }
  }
#pragma unroll
  for (int u = 0; u < 5; ++u)
    *(float2*)(recon + row * IN_DIM + 2 * lane + 128 * u) = acc[u];
}

// ============ launch ============
extern "C" void kernel_launch(void* const* d_in, const int* in_sizes, int n_in,
                              void* d_out, int out_size, void* d_ws, size_t ws_size,
                              hipStream_t stream) {
  const float* x  = (const float*)d_in[0];
  const float* We = (const float*)d_in[1];
  const float* be = (const float*)d_in[2];
  const float* Wd = (const float*)d_in[3];
  const float* bd = (const float*)d_in[4];

  float* recon  = (float*)d_out;
  float* sparse = (float*)d_out + (size_t)BATCH * IN_DIM;   // also dense-latent scratch

  char* ws = (char*)d_ws;
  float*          ws_val = (float*)ws;                                   ws += (size_t)BATCH * KSEL * 4;
  int*            ws_idx = (int*)ws;                                     ws += (size_t)BATCH * KSEL * 4;
  unsigned short* WdT    = (unsigned short*)ws;                          ws += (size_t)LAT_DIM * IN_DIM * 2;
  unsigned short* x_bf   = (unsigned short*)ws;                          ws += (size_t)BATCH * IN_DIM * 2;
  unsigned short* We_bf  = (unsigned short*)ws;

  conv_bf16    <<<(BATCH * IN_DIM / 8 + 255) / 256, 256, 0, stream>>>(x, x_bf, BATCH * IN_DIM / 8);
  conv_bf16    <<<(LAT_DIM * IN_DIM / 8 + 255) / 256, 256, 0, stream>>>(We, We_bf, LAT_DIM * IN_DIM / 8);
  transpose_wd <<<(LAT_DIM / 32) * (IN_DIM / 32), 256, 0, stream>>>(Wd, WdT);
  encoder_mfma <<<(BATCH / 128) * (LAT_DIM / 128), 256, 0, stream>>>(x_bf, We_bf, be, sparse);
  topk2        <<<BATCH / 4, 256, 0, stream>>>(sparse, x, We, be, ws_val, ws_idx);
  decoder_kernel<<<BATCH / 4, 256, 0, stream>>>(ws_val, ws_idx, WdT, bd, recon);
}